// Round 1
// baseline (158.711 us; speedup 1.0000x reference)
//
#include <hip/hip_runtime.h>

// GwcVolume: group-wise correlation cost volume.
// left/right: [B, C, H, W] fp32, C = G*CPG (320 = 40*8)
// out: [B, G, D, H, W] fp32
// out[b,g,d,h,w] = (w>=d) ? (1/CPG) * sum_ch L[b,g,ch,h,w]*R[b,g,ch,h,w-d] : 0

#define BB  2
#define CC  320
#define GG  40
#define CPG 8
#define HH  96
#define WW  312
#define HW  (HH * WW)

// Block: one (b,g,h) row, 320 threads (5 waves), thread t owns w = t.
// LDS: R row in [w][ch] fp32 layout (32 B per w) with XOR swizzle
//   f4 slot = (2*x + c) ^ (x & 7)   (byte addr ^= (x&7)<<4)
// -> any 8 consecutive lanes' ds_read_b128 cover all 32 banks (conflict-free).

__global__ __launch_bounds__(320) void gwc_volume_kernel(
    const float* __restrict__ left,
    const float* __restrict__ right,
    float* __restrict__ out,
    int D)
{
    __shared__ __align__(16) float smem[WW * CPG];   // 9984 B
    float4* s4 = (float4*)smem;

    const int t   = threadIdx.x;
    const int bid = blockIdx.x;        // = bg*HH + h
    const int h   = bid % HH;
    const int bg  = bid / HH;          // b*GG + g

    const size_t chan_base = (size_t)bg * CPG * HW + (size_t)h * WW;

    const bool active = (t < WW);
    const int  w      = active ? t : 0;

    float l0 = 0.f, l1 = 0.f, l2 = 0.f, l3 = 0.f;
    float l4 = 0.f, l5 = 0.f, l6 = 0.f, l7 = 0.f;

    if (active) {
        // Stage right row into LDS (coalesced per channel), swizzled b128 writes.
        const float* rp = right + chan_base + t;
        float r0 = rp[0 * HW], r1 = rp[1 * HW], r2 = rp[2 * HW], r3 = rp[3 * HW];
        float r4 = rp[4 * HW], r5 = rp[5 * HW], r6 = rp[6 * HW], r7 = rp[7 * HW];
        const int k = t & 7;
        s4[(2 * t)     ^ k] = make_float4(r0, r1, r2, r3);
        s4[(2 * t + 1) ^ k] = make_float4(r4, r5, r6, r7);

        // Left values for this thread's w: registers, read once.
        const float* lp = left + chan_base + t;
        l0 = lp[0 * HW]; l1 = lp[1 * HW]; l2 = lp[2 * HW]; l3 = lp[3 * HW];
        l4 = lp[4 * HW]; l5 = lp[5 * HW]; l6 = lp[6 * HW]; l7 = lp[7 * HW];
    }
    __syncthreads();

    // Output pointer for (bg, d=0, h, w); stride HW per d.
    float* op = out + (size_t)bg * D * HW + (size_t)h * WW + w;

    for (int d = 0; d < D; ++d) {
        int x  = w - d;
        int xc = x < 0 ? 0 : x;          // clamp: safe LDS slot, value masked below
        int k  = xc & 7;
        float4 lo = s4[(2 * xc)     ^ k];
        float4 hi = s4[(2 * xc + 1) ^ k];
        float acc = lo.x * l0 + lo.y * l1 + lo.z * l2 + lo.w * l3
                  + hi.x * l4 + hi.y * l5 + hi.z * l6 + hi.w * l7;
        float val = (x >= 0) ? acc * (1.0f / CPG) : 0.0f;
        if (active) *op = val;
        op += HW;
    }
}

extern "C" void kernel_launch(void* const* d_in, const int* in_sizes, int n_in,
                              void* d_out, int out_size, void* d_ws, size_t ws_size,
                              hipStream_t stream) {
    const float* left  = (const float*)d_in[0];
    const float* right = (const float*)d_in[1];
    float* out = (float*)d_out;

    // max_disp lives in device memory (d_in[2]); derive D from out_size on host.
    const int D = out_size / (BB * GG * HH * WW);   // = 48

    dim3 grid(BB * GG * HH);   // 7680 blocks, one per (b,g,h) row
    dim3 block(320);           // 5 waves; thread t -> w = t (t >= WW inactive)
    hipLaunchKernelGGL(gwc_volume_kernel, grid, block, 0, stream,
                       left, right, out, D);
}

// Round 2
// 140.135 us; speedup vs baseline: 1.1326x; 1.1326x over previous
//
#include <hip/hip_runtime.h>

// GwcVolume: group-wise correlation cost volume.
// left/right: [B, C, H, W] fp32, C = G*CPG (320 = 40*8)
// out: [B, G, D, H, W] fp32
// out[b,g,d,h,w] = (w>=d) ? (1/CPG) * sum_ch L[b,g,ch,h,w]*R[b,g,ch,h,w-d] : 0
//
// Strategy: block = (b,g, 4 h-rows). Thread owns 4 consecutive w's (one float4
// store per d). R rows staged in LDS as [r][w][ch] float8 with XOR swizzle
// (f4slot = (2w + half) ^ ((w>>2)&7)) -> conflict-free b128 reads at lane
// stride 4 in w. Register sliding window over d: each d-step loads ONE new
// R-vec (2 b128) instead of 4; d-loop unrolled x4 with register rotation.

#define BB   2
#define CC   320
#define GG   40
#define CPG  8
#define HH   96
#define WW   312
#define HW   (HH * WW)
#define ROWS 4              // h-rows per block
#define W4N  (WW / 4)       // 78 float4-groups per row
#define ACT  (ROWS * W4N)   // 312 active threads
#define NTH  320            // 5 waves
#define F4PR (2 * WW)       // 624 float4 slots per LDS row
#define SCALE (1.0f / CPG)

__global__ __launch_bounds__(NTH) void gwc_volume_kernel(
    const float* __restrict__ left,
    const float* __restrict__ right,
    float* __restrict__ out,
    int D)
{
    __shared__ __align__(16) float4 s4[ROWS * F4PR];   // 39936 B

    const int t    = threadIdx.x;
    const int bid  = blockIdx.x;             // = bg*(HH/ROWS) + hblk
    const int hblk = bid % (HH / ROWS);
    const int bg   = bid / (HH / ROWS);
    const int h0   = hblk * ROWS;

    const bool active = (t < ACT);
    const int  tt = active ? t : 0;
    const int  r  = tt / W4N;                // h-row within block
    const int  w4 = tt - r * W4N;            // float4-group index
    const int  w0 = 4 * w4;

    // start of (bg, ch=0, h0, 0); rows h0..h0+3 are contiguous per channel
    const size_t base = (size_t)bg * CPG * HW + (size_t)h0 * WW;

    // ---- stage R (4 rows x 312 w x 8 ch) into swizzled LDS ----
    // slot s = r*312 + w covers all (r,w); b32 global loads (coalesced),
    // b128 LDS writes (conflict-free under the swizzle).
    for (int s = t; s < ROWS * WW; s += NTH) {
        const int rs = s / WW;
        const int ws = s - rs * WW;
        const float* rp = right + base + s;  // c*HW added per channel
        float v0 = rp[0 * HW], v1 = rp[1 * HW], v2 = rp[2 * HW], v3 = rp[3 * HW];
        float v4 = rp[4 * HW], v5 = rp[5 * HW], v6 = rp[6 * HW], v7 = rp[7 * HW];
        const int k  = (ws >> 2) & 7;
        const int sl = ((2 * ws) ^ k) + rs * F4PR;
        s4[sl]     = make_float4(v0, v1, v2, v3);
        s4[sl ^ 1] = make_float4(v4, v5, v6, v7);   // (2w+1)^k == ((2w)^k)^1
    }

    // ---- L values for this thread's 4 w's, pre-scaled by 1/CPG ----
    float LJ[4][8];
    #pragma unroll
    for (int c = 0; c < CPG; ++c) {
        float4 lv = make_float4(0.f, 0.f, 0.f, 0.f);
        if (active)
            lv = *(const float4*)(left + base + (size_t)c * HW + (size_t)r * WW + w0);
        LJ[0][c] = lv.x * SCALE;
        LJ[1][c] = lv.y * SCALE;
        LJ[2][c] = lv.z * SCALE;
        LJ[3][c] = lv.w * SCALE;
    }

    __syncthreads();

    const float4* f4row = s4 + r * F4PR;

    // read R-vec (8 ch) for column x; clamp x<0 (value masked at store)
    #define RVEC(x, A, B) do {                       \
        int xi_ = (x) < 0 ? 0 : (x);                 \
        int k_  = (xi_ >> 2) & 7;                    \
        int sl_ = (2 * xi_) ^ k_;                    \
        A = f4row[sl_];                              \
        B = f4row[sl_ ^ 1];                          \
    } while (0)

    #define DOT8(j, A, B) (LJ[j][0]*A.x + LJ[j][1]*A.y + LJ[j][2]*A.z + LJ[j][3]*A.w \
                         + LJ[j][4]*B.x + LJ[j][5]*B.y + LJ[j][6]*B.z + LJ[j][7]*B.w)

    #define STEP(A_0,B_0, A_1,B_1, A_2,B_2, A_3,B_3) do {      \
        float4 st_;                                            \
        st_.x = (x0     >= 0) ? DOT8(0, A_0, B_0) : 0.0f;      \
        st_.y = (x0 + 1 >= 0) ? DOT8(1, A_1, B_1) : 0.0f;      \
        st_.z = (x0 + 2 >= 0) ? DOT8(2, A_2, B_2) : 0.0f;      \
        st_.w = (x0 + 3 >= 0) ? DOT8(3, A_3, B_3) : 0.0f;      \
        if (active) *(float4*)op = st_;                        \
        op += HW;                                              \
    } while (0)

    // init window: V_j = R[w0+j]  (all indices >= 0)
    float4 A0,B0, A1,B1, A2,B2, A3,B3;
    RVEC(w0 + 0, A0, B0);
    RVEC(w0 + 1, A1, B1);
    RVEC(w0 + 2, A2, B2);
    RVEC(w0 + 3, A3, B3);

    float* op = out + (size_t)bg * D * HW + (size_t)(h0 + r) * WW + w0;
    int x0 = w0;                       // = w0 - d

    const int nq = D >> 2;
    for (int q = 0; q < nq; ++q) {
        STEP(A0,B0, A1,B1, A2,B2, A3,B3);  RVEC(x0 - 1, A3, B3);  x0 -= 1;
        STEP(A3,B3, A0,B0, A1,B1, A2,B2);  RVEC(x0 - 1, A2, B2);  x0 -= 1;
        STEP(A2,B2, A3,B3, A0,B0, A1,B1);  RVEC(x0 - 1, A1, B1);  x0 -= 1;
        STEP(A1,B1, A2,B2, A3,B3, A0,B0);  RVEC(x0 - 1, A0, B0);  x0 -= 1;
    }

    // remainder for D % 4 != 0 (dead for D=48, kept for safety)
    for (int d = nq * 4; d < D; ++d) {
        const int xb = w0 - d;
        float4 Xa, Xb, st_;
        RVEC(xb + 0, Xa, Xb); st_.x = (xb     >= 0) ? DOT8(0, Xa, Xb) : 0.0f;
        RVEC(xb + 1, Xa, Xb); st_.y = (xb + 1 >= 0) ? DOT8(1, Xa, Xb) : 0.0f;
        RVEC(xb + 2, Xa, Xb); st_.z = (xb + 2 >= 0) ? DOT8(2, Xa, Xb) : 0.0f;
        RVEC(xb + 3, Xa, Xb); st_.w = (xb + 3 >= 0) ? DOT8(3, Xa, Xb) : 0.0f;
        if (active) *(float4*)op = st_;
        op += HW;
    }

    #undef RVEC
    #undef DOT8
    #undef STEP
}

extern "C" void kernel_launch(void* const* d_in, const int* in_sizes, int n_in,
                              void* d_out, int out_size, void* d_ws, size_t ws_size,
                              hipStream_t stream) {
    const float* left  = (const float*)d_in[0];
    const float* right = (const float*)d_in[1];
    float* out = (float*)d_out;

    // max_disp lives in device memory (d_in[2]); derive D from out_size on host.
    const int D = out_size / (BB * GG * HH * WW);   // = 48

    dim3 grid(BB * GG * (HH / ROWS));   // 1920 blocks: one per (b,g,4-row h-band)
    dim3 block(NTH);                    // 5 waves; 312 active threads
    hipLaunchKernelGGL(gwc_volume_kernel, grid, block, 0, stream,
                       left, right, out, D);
}